// Round 1
// 496.463 us; speedup vs baseline: 1.0505x; 1.0505x over previous
//
#include <hip/hip_runtime.h>
#include <math.h>

#define NB 16
#define NL 4096
#define NH 8
#define NI 64
#define NO 64
#define NM 64
#define QUARTER 1024
#define STEP 1.5339807878856412e-3f  // 2*pi/4096

using bf16_t = __bf16;
using bf16x8 = __attribute__((ext_vector_type(8))) __bf16;
using f32x16 = __attribute__((ext_vector_type(16))) float;

#define LDW 136   // LDS row stride (bf16 elems) = 272 B = 17*16 -> conflict-free b128
#define TMC 128   // mc entries per l-row in twiddle tables

// ---------------------------------------------------------------------------
// k_tab: once per launch.
//   ctab[4096]        : fp32 cos(2*pi*idx/4096)   (used by k_fwd; sin via +3072)
//   Thi/Tlo[l][mc]    : bf16 hi/lo split of T, T[l][2m]=cos(2pi m l/4096),
//                       T[l][2m+1]=-sin(2pi m l/4096)  (B-operand, l-major)
// ---------------------------------------------------------------------------
__global__ __launch_bounds__(256) void k_tab(float* __restrict__ ctab,
                                             bf16_t* __restrict__ Thi,
                                             bf16_t* __restrict__ Tlo) {
  const int gid = blockIdx.x * 256 + threadIdx.x;   // 0 .. 524287
  const int l = gid >> 7, mc = gid & 127, m = mc >> 1;
  const int p = (m * l) & 4095;
  const float c = cosf((float)p * STEP);
  const float s = cosf((float)((p + 3072) & 4095) * STEP);  // = sin(theta)
  const float val = (mc & 1) ? -s : c;
  const bf16_t hi = (bf16_t)val;
  Thi[gid] = hi;
  Tlo[gid] = (bf16_t)(val - (float)hi);
  if (gid < 4096) ctab[gid] = cosf((float)gid * STEP);
}

// ---------------------------------------------------------------------------
// K1: forward truncated DFT with one radix-4 decimation over l. (unchanged
// except: cos table loaded from global instead of 4096 cosf per block)
// ---------------------------------------------------------------------------
__global__ __launch_bounds__(256) void k_fwd(const float* __restrict__ q,
                                             float* __restrict__ partial,
                                             const float* __restrict__ ctab,
                                             int LCF, int CHUNK) {
  const int lc = blockIdx.x, h = blockIdx.y, b = blockIdx.z;
  const int t = threadIdx.x;
  __shared__ float ct[4096];        // plain cos table (reads are wave-broadcast)
  __shared__ float4 prep[16][64];   // {S, D, G, H} per [l'_local][i]

  for (int idx = t; idx < 4096; idx += 256) ct[idx] = ctab[idx];

  const int ig = t & 15;            // i-group; thread's i = ig + 16*j
  const int m0 = (t >> 4) << 2;     // 4 consecutive m -> residues 0,1,2,3
  float ar[4][4], ai[4][4];         // [k=residue][j=i]
#pragma unroll
  for (int k = 0; k < 4; ++k)
#pragma unroll
    for (int j = 0; j < 4; ++j) { ar[k][j] = 0.f; ai[k][j] = 0.f; }

  const int lstart = lc * CHUNK;

  for (int tt = 0; tt < CHUNK; tt += 16) {
    __syncthreads();  // previous tile's readers done before overwrite
    {
      const int iA = t & 63;
#pragma unroll
      for (int c = 0; c < 4; ++c) {
        const int lloc = (t >> 6) + (c << 2);
        const int labs = lstart + tt + lloc;        // l' in [0,1024)
        const float* qp = q + (((size_t)b * NL + labs) * NH + h) * NI + iA;
        const float q0 = qp[0];
        const float q1 = qp[(size_t)QUARTER * NH * NI];
        const float q2 = qp[(size_t)2 * QUARTER * NH * NI];
        const float q3 = qp[(size_t)3 * QUARTER * NH * NI];
        const float E = q0 + q2, F = q1 + q3;
        prep[lloc][iA] = make_float4(E + F, E - F, q0 - q2, q1 - q3);
      }
    }
    __syncthreads();
#pragma unroll 2
    for (int ll = 0; ll < 16; ++ll) {
      const int la = lstart + tt + ll;
      const int p0 = (m0 * la) & 4095;
      const int p1 = (p0 + la) & 4095;
      const int p2 = (p1 + la) & 4095;
      const int p3 = (p2 + la) & 4095;
      const float c0 = ct[p0], s0 = ct[(p0 + 3072) & 4095];
      const float c1 = ct[p1], s1 = ct[(p1 + 3072) & 4095];
      const float c2 = ct[p2], s2 = ct[(p2 + 3072) & 4095];
      const float c3 = ct[p3], s3 = ct[(p3 + 3072) & 4095];
#pragma unroll
      for (int j = 0; j < 4; ++j) {
        const float4 f = prep[ll][ig + (j << 4)];
        ar[0][j] = fmaf(f.x, c0, ar[0][j]);
        ai[0][j] = fmaf(-f.x, s0, ai[0][j]);
        ar[1][j] = fmaf(f.z, c1, ar[1][j]);
        ar[1][j] = fmaf(-f.w, s1, ar[1][j]);
        ai[1][j] = fmaf(-f.z, s1, ai[1][j]);
        ai[1][j] = fmaf(-f.w, c1, ai[1][j]);
        ar[2][j] = fmaf(f.y, c2, ar[2][j]);
        ai[2][j] = fmaf(-f.y, s2, ai[2][j]);
        ar[3][j] = fmaf(f.z, c3, ar[3][j]);
        ar[3][j] = fmaf(f.w, s3, ar[3][j]);
        ai[3][j] = fmaf(f.w, c3, ai[3][j]);
        ai[3][j] = fmaf(-f.z, s3, ai[3][j]);
      }
    }
  }
  float2* dst = (float2*)partial + (((size_t)b * NH + h) * LCF + lc) * (NM * NI);
#pragma unroll
  for (int k = 0; k < 4; ++k)
#pragma unroll
    for (int j = 0; j < 4; ++j)
      dst[(m0 + k) * NI + (ig + (j << 4))] = make_float2(ar[k][j], ai[k][j]);
}

// ---------------------------------------------------------------------------
// K2: reduce partials over lc, then complex mix (unchanged).
// ---------------------------------------------------------------------------
__global__ __launch_bounds__(256) void k_mix(const float* __restrict__ partial,
                                             const float* __restrict__ w1,
                                             const float* __restrict__ w2,
                                             float* __restrict__ out2, int LCF) {
  const int og = blockIdx.x, h = blockIdx.y, b = blockIdx.z;
  const int t = threadIdx.x;
  __shared__ float sel_s[2][64][65];   // [re/im][i][m], +1 pad on m

  const float* src = partial + ((size_t)b * NH + h) * LCF * (NM * NI * 2);
  for (int u = t; u < NM * NI * 2; u += 256) {
    float v = 0.f;
    for (int lcx = 0; lcx < LCF; ++lcx) v += src[(size_t)lcx * (NM * NI * 2) + u];
    sel_s[u & 1][(u >> 1) & 63][u >> 7] = v;
  }
  __syncthreads();

  const int o = og * 16 + (t >> 4);
  const int mt = t & 15;
  float ar[4] = {0.f, 0.f, 0.f, 0.f}, ai[4] = {0.f, 0.f, 0.f, 0.f};
  for (int i = 0; i < NI; ++i) {
    const float* w1p = w1 + (((size_t)h * NI + i) * NO + o) * NM;
    const float* w2p = w2 + (((size_t)h * NI + i) * NO + o) * NM;
#pragma unroll
    for (int k = 0; k < 4; ++k) {
      const int m = mt + (k << 4);
      const float re = sel_s[0][i][m];
      const float im = sel_s[1][i][m];
      const float a = w1p[m];
      const float bb = w2p[m];
      ar[k] = fmaf(re, a, ar[k]);
      ar[k] = fmaf(-im, bb, ar[k]);
      ai[k] = fmaf(re, bb, ai[k]);
      ai[k] = fmaf(im, a, ai[k]);
    }
  }
  float2* dst = (float2*)out2 + ((size_t)b * NH + h) * (NM * NO);
#pragma unroll
  for (int k = 0; k < 4; ++k)
    dst[(mt + (k << 4)) * NO + o] = make_float2(ar[k], ai[k]);
}

// ---------------------------------------------------------------------------
// K3: inverse truncated DFT as MFMA GEMM.
//   out[o][l] = sum_mc W[o][mc] * T[mc][l],  W[o][2m]=fac*Re(c), W[o][2m+1]=fac*Im(c)
//   M=64 (o), N=l, K=128 (mc). bf16 hi/lo split, 3 products, fp32 acc.
// Block = (b,h) x 256-l tile; wave = 64o x 64l (2x2 frags of 32x32).
// A (W) staged in LDS (row pad 272 B = 17 banks -> conflict-free ds_read_b128);
// B (T) streamed straight from global (2 MB tables, L2-resident).
// ---------------------------------------------------------------------------
__global__ __launch_bounds__(256) void k_inv(const float* __restrict__ out2,
                                             const bf16_t* __restrict__ Thi,
                                             const bf16_t* __restrict__ Tlo,
                                             float* __restrict__ xout) {
  const int lb = blockIdx.x, h = blockIdx.y, b = blockIdx.z;
  const int t = threadIdx.x;
  __shared__ bf16_t Whi[64 * LDW];
  __shared__ bf16_t Wlo[64 * LDW];

  {  // stage W = fac * out2, transposed to [o][mc], split hi/lo
    const float2* src = (const float2*)out2 + ((size_t)b * NH + h) * (NM * NO);
    for (int u = t; u < NM * NO; u += 256) {
      const int m = u >> 6, o = u & 63;
      const float fac = (m == 0 ? 1.0f : 2.0f) * (1.0f / 4096.0f);
      const float2 cc = src[u];
      const float re = cc.x * fac, im = cc.y * fac;
      const bf16_t reh = (bf16_t)re, imh = (bf16_t)im;
      Whi[o * LDW + 2 * m] = reh;
      Whi[o * LDW + 2 * m + 1] = imh;
      Wlo[o * LDW + 2 * m] = (bf16_t)(re - (float)reh);
      Wlo[o * LDW + 2 * m + 1] = (bf16_t)(im - (float)imh);
    }
  }
  __syncthreads();

  const int w = t >> 6, lane = t & 63;
  const int lrow = lane & 31;        // A: o-row in tile; B: l-col in tile
  const int kh = (lane >> 5) << 3;   // k sub-offset: 0 or 8
  const int lwave = (lb << 8) + (w << 6);  // wave's 64-wide l base

  f32x16 acc[2][2] = {};             // [of][lf]

#pragma unroll
  for (int ks = 0; ks < 8; ++ks) {
    const int kb = ks * 16 + kh;
    const bf16x8 ah0 = *(const bf16x8*)&Whi[lrow * LDW + kb];
    const bf16x8 ah1 = *(const bf16x8*)&Whi[(lrow + 32) * LDW + kb];
    const bf16x8 al0 = *(const bf16x8*)&Wlo[lrow * LDW + kb];
    const bf16x8 al1 = *(const bf16x8*)&Wlo[(lrow + 32) * LDW + kb];
    const size_t r0 = (size_t)(lwave + lrow) * TMC + kb;
    const size_t r1 = (size_t)(lwave + 32 + lrow) * TMC + kb;
    const bf16x8 bh0 = *(const bf16x8*)&Thi[r0];
    const bf16x8 bh1 = *(const bf16x8*)&Thi[r1];
    const bf16x8 bl0 = *(const bf16x8*)&Tlo[r0];
    const bf16x8 bl1 = *(const bf16x8*)&Tlo[r1];
#define MM(a, bb, c) c = __builtin_amdgcn_mfma_f32_32x32x16_bf16(a, bb, c, 0, 0, 0)
    MM(ah0, bh0, acc[0][0]); MM(ah0, bl0, acc[0][0]); MM(al0, bh0, acc[0][0]);
    MM(ah0, bh1, acc[0][1]); MM(ah0, bl1, acc[0][1]); MM(al0, bh1, acc[0][1]);
    MM(ah1, bh0, acc[1][0]); MM(ah1, bl0, acc[1][0]); MM(al1, bh0, acc[1][0]);
    MM(ah1, bh1, acc[1][1]); MM(ah1, bl1, acc[1][1]); MM(al1, bh1, acc[1][1]);
#undef MM
  }

  // C/D layout (m101-verified): col = lane&31, row = (reg&3)+8*(reg>>2)+4*(lane>>5)
  float* obase = xout + ((size_t)b * NH + h) * NO * (size_t)NL;
#pragma unroll
  for (int of = 0; of < 2; ++of)
#pragma unroll
    for (int lf = 0; lf < 2; ++lf) {
      const int lg = lwave + lf * 32 + lrow;
#pragma unroll
      for (int r = 0; r < 16; ++r) {
        const int o = of * 32 + (r & 3) + 8 * (r >> 2) + 4 * (lane >> 5);
        obase[(size_t)o * NL + lg] = acc[of][lf][r];
      }
    }
}

extern "C" void kernel_launch(void* const* d_in, const int* in_sizes, int n_in,
                              void* d_out, int out_size, void* d_ws, size_t ws_size,
                              hipStream_t stream) {
  const float* q  = (const float*)d_in[0];
  // d_in[1]=k, d_in[2]=v, d_in[3]=mask unused by the reference
  const float* w1 = (const float*)d_in[4];
  const float* w2 = (const float*)d_in[5];
  float* out = (float*)d_out;

  const size_t out2Elems = (size_t)NB * NH * NM * NO * 2;          // 1,048,576 floats
  const size_t tElems = (size_t)NL * TMC;                          // 524,288 bf16 per table
  const size_t tabFloats = 4096 + (2 * tElems * sizeof(bf16_t)) / sizeof(float);
  int LCF = 1;
  const int cands[4] = {8, 4, 2, 1};
  for (int ci = 0; ci < 4; ++ci) {
    const size_t pe = (size_t)NB * NH * cands[ci] * NM * NI * 2;
    if ((pe + out2Elems + tabFloats) * sizeof(float) <= ws_size) { LCF = cands[ci]; break; }
  }
  const size_t partialElems = (size_t)NB * NH * LCF * NM * NI * 2;
  float* partial = (float*)d_ws;
  float* out2 = partial + partialElems;
  float* ctab = out2 + out2Elems;
  bf16_t* Thi = (bf16_t*)(ctab + 4096);
  bf16_t* Tlo = Thi + tElems;

  dim3 blk(256);
  k_tab<<<dim3((unsigned)(tElems / 256)), blk, 0, stream>>>(ctab, Thi, Tlo);
  k_fwd<<<dim3(LCF, NH, NB), blk, 0, stream>>>(q, partial, ctab, LCF, QUARTER / LCF);
  k_mix<<<dim3(4, NH, NB), blk, 0, stream>>>(partial, w1, w2, out2, LCF);
  k_inv<<<dim3(16, NH, NB), blk, 0, stream>>>(out2, Thi, Tlo, out);
}

// Round 2
// 486.895 us; speedup vs baseline: 1.0712x; 1.0197x over previous
//
#include <hip/hip_runtime.h>
#include <math.h>

#define NB 16
#define NL 4096
#define NH 8
#define NI 64
#define NO 64
#define NM 64
#define STEP 1.5339807878856412e-3f  // 2*pi/4096

using bf16_t = __bf16;
using bf16x8 = __attribute__((ext_vector_type(8))) __bf16;
using f32x16 = __attribute__((ext_vector_type(16))) float;

#define LDW 136   // k_inv LDS row stride (bf16) = 272 B = 17*16 -> conflict-free b128
#define TMC 128   // mc entries per l-row in T (l-major) table

// ---------------------------------------------------------------------------
// k_tab: once per launch. Twiddle tables, bf16 hi/lo split:
//   T  [l][mc]  (l-major,  B-operand of k_inv):  T[l][2m]=cos,  T[l][2m+1]=-sin
//   Tf [mc][l]  (mc-major, A-operand of k_fwd):  same values, transposed layout
// ---------------------------------------------------------------------------
__global__ __launch_bounds__(256) void k_tab(bf16_t* __restrict__ Thi,
                                             bf16_t* __restrict__ Tlo,
                                             bf16_t* __restrict__ Tfhi,
                                             bf16_t* __restrict__ Tflo) {
  const int gid = blockIdx.x * 256 + threadIdx.x;   // 0 .. 524287
  {  // l-major
    const int l = gid >> 7, mc = gid & 127, m = mc >> 1;
    const int p = (m * l) & 4095;
    const float c = cosf((float)p * STEP);
    const float s = cosf((float)((p + 3072) & 4095) * STEP);  // = sin
    const float val = (mc & 1) ? -s : c;
    const bf16_t hi = (bf16_t)val;
    Thi[gid] = hi;
    Tlo[gid] = (bf16_t)(val - (float)hi);
  }
  {  // mc-major
    const int mc = gid >> 12, l = gid & 4095, m = mc >> 1;
    const int p = (m * l) & 4095;
    const float c = cosf((float)p * STEP);
    const float s = cosf((float)((p + 3072) & 4095) * STEP);
    const float val = (mc & 1) ? -s : c;
    const bf16_t hi = (bf16_t)val;
    Tfhi[gid] = hi;
    Tflo[gid] = (bf16_t)(val - (float)hi);
  }
}

// ---------------------------------------------------------------------------
// K1: forward truncated DFT as MFMA GEMM.
//   sel[mc][i] = sum_l Tf[mc][l] * q[l][i],  M=128 (mc), N=64 (i), K=4096 (l),
//   K split over LCF blocks; partial[b][h][lc][m][i] (float2) reduced by k_mix.
// A (Tf) streamed from global (2 MB, L2-resident). B (q) staged to LDS as
// bf16 hi/lo, transposed to [i][l]: l-pairs packed in u32, row stride 33 words
// -> conflict-free ds_read_b128. bf16 hi/lo split, 3 MFMA products, fp32 acc.
// ---------------------------------------------------------------------------
__global__ __launch_bounds__(256) void k_fwd(const float* __restrict__ q,
                                             float* __restrict__ partial,
                                             const bf16_t* __restrict__ Tfhi,
                                             const bf16_t* __restrict__ Tflo,
                                             int LCF, int KCH) {
  const int lc = blockIdx.x, h = blockIdx.y, b = blockIdx.z;
  const int t = threadIdx.x;
  __shared__ uint32_t Bh[64][33], Bl[64][33];   // [i][l-pair], +1 pad word

  const int w = t >> 6, lane = t & 63;
  const int arow = lane & 31;        // A: mc row in tile; B: i col in tile
  const int kh = (lane >> 5) << 3;   // k sub-offset: 0 or 8
  const int lp = t & 31;             // staging: l-pair index
  const int i0 = (t >> 5) << 3;      // staging: 8 i values per thread

  f32x16 acc[2] = {};                // [i-half]

  const int lbase0 = lc * KCH;
  const bf16_t* Ah = Tfhi + (size_t)(w * 32 + arow) * NL + lbase0 + kh;
  const bf16_t* Al = Tflo + (size_t)(w * 32 + arow) * NL + lbase0 + kh;

  for (int ks = 0; ks < KCH; ks += 64) {
    __syncthreads();  // previous tile's readers done before overwrite
    {
      const int l0 = lbase0 + ks + (lp << 1);
      const float* qp = q + (((size_t)b * NL + l0) * NH + h) * NI + i0;
      const float4 a0 = *(const float4*)qp;
      const float4 a1 = *(const float4*)(qp + 4);
      const float4 b0 = *(const float4*)(qp + NH * NI);
      const float4 b1 = *(const float4*)(qp + NH * NI + 4);
      const float va[8] = {a0.x, a0.y, a0.z, a0.w, a1.x, a1.y, a1.z, a1.w};
      const float vb[8] = {b0.x, b0.y, b0.z, b0.w, b1.x, b1.y, b1.z, b1.w};
#pragma unroll
      for (int j = 0; j < 8; ++j) {
        const bf16_t h0 = (bf16_t)va[j], h1 = (bf16_t)vb[j];
        const bf16_t g0 = (bf16_t)(va[j] - (float)h0);
        const bf16_t g1 = (bf16_t)(vb[j] - (float)h1);
        union { bf16_t u[2]; uint32_t w32; } ph, pl;
        ph.u[0] = h0; ph.u[1] = h1;       // low half = even l
        pl.u[0] = g0; pl.u[1] = g1;
        Bh[i0 + j][lp] = ph.w32;
        Bl[i0 + j][lp] = pl.w32;
      }
    }
    __syncthreads();
#pragma unroll
    for (int kk = 0; kk < 4; ++kk) {
      const bf16x8 ah = *(const bf16x8*)(Ah + ks + kk * 16);
      const bf16x8 al = *(const bf16x8*)(Al + ks + kk * 16);
      const int wd = (kk * 16 + kh) >> 1;
      const bf16x8 bh0 = *(const bf16x8*)&Bh[arow][wd];
      const bf16x8 bl0 = *(const bf16x8*)&Bl[arow][wd];
      const bf16x8 bh1 = *(const bf16x8*)&Bh[arow + 32][wd];
      const bf16x8 bl1 = *(const bf16x8*)&Bl[arow + 32][wd];
#define MM(a, bb, c) c = __builtin_amdgcn_mfma_f32_32x32x16_bf16(a, bb, c, 0, 0, 0)
      MM(ah, bh0, acc[0]); MM(ah, bl0, acc[0]); MM(al, bh0, acc[0]);
      MM(ah, bh1, acc[1]); MM(ah, bl1, acc[1]); MM(al, bh1, acc[1]);
#undef MM
    }
  }

  // C/D layout (verified via k_inv): col = lane&31, row = (reg&3)+8*(reg>>2)+4*(lane>>5)
  float* pdst = partial + (((size_t)b * NH + h) * LCF + lc) * (NM * NI * 2);
#pragma unroll
  for (int ihf = 0; ihf < 2; ++ihf)
#pragma unroll
    for (int r = 0; r < 16; ++r) {
      const int mc = w * 32 + (r & 3) + 8 * (r >> 2) + 4 * (lane >> 5);
      const int i = arow + ihf * 32;
      pdst[(mc >> 1) * (NI * 2) + i * 2 + (mc & 1)] = acc[ihf][r];
    }
}

// ---------------------------------------------------------------------------
// K2: reduce partials over lc, then complex mix (unchanged).
// ---------------------------------------------------------------------------
__global__ __launch_bounds__(256) void k_mix(const float* __restrict__ partial,
                                             const float* __restrict__ w1,
                                             const float* __restrict__ w2,
                                             float* __restrict__ out2, int LCF) {
  const int og = blockIdx.x, h = blockIdx.y, b = blockIdx.z;
  const int t = threadIdx.x;
  __shared__ float sel_s[2][64][65];   // [re/im][i][m], +1 pad on m

  const float* src = partial + ((size_t)b * NH + h) * LCF * (NM * NI * 2);
  for (int u = t; u < NM * NI * 2; u += 256) {
    float v = 0.f;
    for (int lcx = 0; lcx < LCF; ++lcx) v += src[(size_t)lcx * (NM * NI * 2) + u];
    sel_s[u & 1][(u >> 1) & 63][u >> 7] = v;
  }
  __syncthreads();

  const int o = og * 16 + (t >> 4);
  const int mt = t & 15;
  float ar[4] = {0.f, 0.f, 0.f, 0.f}, ai[4] = {0.f, 0.f, 0.f, 0.f};
  for (int i = 0; i < NI; ++i) {
    const float* w1p = w1 + (((size_t)h * NI + i) * NO + o) * NM;
    const float* w2p = w2 + (((size_t)h * NI + i) * NO + o) * NM;
#pragma unroll
    for (int k = 0; k < 4; ++k) {
      const int m = mt + (k << 4);
      const float re = sel_s[0][i][m];
      const float im = sel_s[1][i][m];
      const float a = w1p[m];
      const float bb = w2p[m];
      ar[k] = fmaf(re, a, ar[k]);
      ar[k] = fmaf(-im, bb, ar[k]);
      ai[k] = fmaf(re, bb, ai[k]);
      ai[k] = fmaf(im, a, ai[k]);
    }
  }
  float2* dst = (float2*)out2 + ((size_t)b * NH + h) * (NM * NO);
#pragma unroll
  for (int k = 0; k < 4; ++k)
    dst[(mt + (k << 4)) * NO + o] = make_float2(ar[k], ai[k]);
}

// ---------------------------------------------------------------------------
// K3: inverse truncated DFT as MFMA GEMM (unchanged from round 1).
//   out[o][l] = sum_mc W[o][mc] * T[l][mc]
// ---------------------------------------------------------------------------
__global__ __launch_bounds__(256) void k_inv(const float* __restrict__ out2,
                                             const bf16_t* __restrict__ Thi,
                                             const bf16_t* __restrict__ Tlo,
                                             float* __restrict__ xout) {
  const int lb = blockIdx.x, h = blockIdx.y, b = blockIdx.z;
  const int t = threadIdx.x;
  __shared__ bf16_t Whi[64 * LDW];
  __shared__ bf16_t Wlo[64 * LDW];

  {  // stage W = fac * out2, transposed to [o][mc], split hi/lo
    const float2* src = (const float2*)out2 + ((size_t)b * NH + h) * (NM * NO);
    for (int u = t; u < NM * NO; u += 256) {
      const int m = u >> 6, o = u & 63;
      const float fac = (m == 0 ? 1.0f : 2.0f) * (1.0f / 4096.0f);
      const float2 cc = src[u];
      const float re = cc.x * fac, im = cc.y * fac;
      const bf16_t reh = (bf16_t)re, imh = (bf16_t)im;
      Whi[o * LDW + 2 * m] = reh;
      Whi[o * LDW + 2 * m + 1] = imh;
      Wlo[o * LDW + 2 * m] = (bf16_t)(re - (float)reh);
      Wlo[o * LDW + 2 * m + 1] = (bf16_t)(im - (float)imh);
    }
  }
  __syncthreads();

  const int w = t >> 6, lane = t & 63;
  const int lrow = lane & 31;        // A: o-row in tile; B: l-col in tile
  const int kh = (lane >> 5) << 3;   // k sub-offset: 0 or 8
  const int lwave = (lb << 8) + (w << 6);  // wave's 64-wide l base

  f32x16 acc[2][2] = {};             // [of][lf]

#pragma unroll
  for (int ks = 0; ks < 8; ++ks) {
    const int kb = ks * 16 + kh;
    const bf16x8 ah0 = *(const bf16x8*)&Whi[lrow * LDW + kb];
    const bf16x8 ah1 = *(const bf16x8*)&Whi[(lrow + 32) * LDW + kb];
    const bf16x8 al0 = *(const bf16x8*)&Wlo[lrow * LDW + kb];
    const bf16x8 al1 = *(const bf16x8*)&Wlo[(lrow + 32) * LDW + kb];
    const size_t r0 = (size_t)(lwave + lrow) * TMC + kb;
    const size_t r1 = (size_t)(lwave + 32 + lrow) * TMC + kb;
    const bf16x8 bh0 = *(const bf16x8*)&Thi[r0];
    const bf16x8 bh1 = *(const bf16x8*)&Thi[r1];
    const bf16x8 bl0 = *(const bf16x8*)&Tlo[r0];
    const bf16x8 bl1 = *(const bf16x8*)&Tlo[r1];
#define MM(a, bb, c) c = __builtin_amdgcn_mfma_f32_32x32x16_bf16(a, bb, c, 0, 0, 0)
    MM(ah0, bh0, acc[0][0]); MM(ah0, bl0, acc[0][0]); MM(al0, bh0, acc[0][0]);
    MM(ah0, bh1, acc[0][1]); MM(ah0, bl1, acc[0][1]); MM(al0, bh1, acc[0][1]);
    MM(ah1, bh0, acc[1][0]); MM(ah1, bl0, acc[1][0]); MM(al1, bh0, acc[1][0]);
    MM(ah1, bh1, acc[1][1]); MM(ah1, bl1, acc[1][1]); MM(al1, bh1, acc[1][1]);
#undef MM
  }

  float* obase = xout + ((size_t)b * NH + h) * NO * (size_t)NL;
#pragma unroll
  for (int of = 0; of < 2; ++of)
#pragma unroll
    for (int lf = 0; lf < 2; ++lf) {
      const int lg = lwave + lf * 32 + lrow;
#pragma unroll
      for (int r = 0; r < 16; ++r) {
        const int o = of * 32 + (r & 3) + 8 * (r >> 2) + 4 * (lane >> 5);
        obase[(size_t)o * NL + lg] = acc[of][lf][r];
      }
    }
}

extern "C" void kernel_launch(void* const* d_in, const int* in_sizes, int n_in,
                              void* d_out, int out_size, void* d_ws, size_t ws_size,
                              hipStream_t stream) {
  const float* q  = (const float*)d_in[0];
  // d_in[1]=k, d_in[2]=v, d_in[3]=mask unused by the reference
  const float* w1 = (const float*)d_in[4];
  const float* w2 = (const float*)d_in[5];
  float* out = (float*)d_out;

  const size_t out2Elems = (size_t)NB * NH * NM * NO * 2;  // 1,048,576 floats
  const size_t tE = 524288;                                // entries per bf16 table
  const size_t tabFloats = (4 * tE) / 2;                   // 4 bf16 tables -> floats
  int LCF = 1;
  const int cands[4] = {8, 4, 2, 1};
  for (int ci = 0; ci < 4; ++ci) {
    const size_t pe = (size_t)NB * NH * cands[ci] * NM * NI * 2;
    if ((pe + out2Elems + tabFloats) * sizeof(float) <= ws_size) { LCF = cands[ci]; break; }
  }
  const size_t partialElems = (size_t)NB * NH * LCF * NM * NI * 2;
  float* partial = (float*)d_ws;
  float* out2 = partial + partialElems;
  bf16_t* Thi = (bf16_t*)(out2 + out2Elems);
  bf16_t* Tlo = Thi + tE;
  bf16_t* Tfhi = Tlo + tE;
  bf16_t* Tflo = Tfhi + tE;

  dim3 blk(256);
  k_tab<<<dim3((unsigned)(tE / 256)), blk, 0, stream>>>(Thi, Tlo, Tfhi, Tflo);
  k_fwd<<<dim3(LCF, NH, NB), blk, 0, stream>>>(q, partial, Tfhi, Tflo, LCF, NL / LCF);
  k_mix<<<dim3(4, NH, NB), blk, 0, stream>>>(partial, w1, w2, out2, LCF);
  k_inv<<<dim3(16, NH, NB), blk, 0, stream>>>(out2, Thi, Tlo, out);
}

// Round 4
// 432.516 us; speedup vs baseline: 1.2058x; 1.1257x over previous
//
#include <hip/hip_runtime.h>
#include <math.h>

#define NB 16
#define NL 4096
#define NH 8
#define NI 64
#define NO 64
#define NM 64
#define STEP 1.5339807878856412e-3f  // 2*pi/4096

using bf16_t = __bf16;
using bf16x8 = __attribute__((ext_vector_type(8))) __bf16;
using f32x4  = __attribute__((ext_vector_type(4))) float;
using f32x16 = __attribute__((ext_vector_type(16))) float;

#define LDW 136   // k_inv LDS row stride (bf16) = 272 B = 17*16 -> conflict-free b128
#define TMC 128   // mc entries per l-row in T (l-major) table

__device__ __forceinline__ uint32_t pk2(float x, float y) {
  union { bf16_t b[2]; uint32_t u; } r;
  r.b[0] = (bf16_t)x; r.b[1] = (bf16_t)y; return r.u;
}

// ---------------------------------------------------------------------------
// k_tab: twiddle tables, bf16 hi/lo split.
//   T  [l][mc]  (l-major,  B-operand of k_inv):  T[l][2m]=cos,  T[l][2m+1]=-sin
//   Tf [mc][l]  (mc-major, A-operand of k_fwd)
// ---------------------------------------------------------------------------
__global__ __launch_bounds__(256) void k_tab(bf16_t* __restrict__ Thi,
                                             bf16_t* __restrict__ Tlo,
                                             bf16_t* __restrict__ Tfhi,
                                             bf16_t* __restrict__ Tflo) {
  const int gid = blockIdx.x * 256 + threadIdx.x;   // 0 .. 524287
  {  // l-major
    const int l = gid >> 7, mc = gid & 127, m = mc >> 1;
    const int p = (m * l) & 4095;
    const float c = cosf((float)p * STEP);
    const float s = cosf((float)((p + 3072) & 4095) * STEP);  // = sin
    const float val = (mc & 1) ? -s : c;
    const bf16_t hi = (bf16_t)val;
    Thi[gid] = hi;
    Tlo[gid] = (bf16_t)(val - (float)hi);
  }
  {  // mc-major
    const int mc = gid >> 12, l = gid & 4095, m = mc >> 1;
    const int p = (m * l) & 4095;
    const float c = cosf((float)p * STEP);
    const float s = cosf((float)((p + 3072) & 4095) * STEP);
    const float val = (mc & 1) ? -s : c;
    const bf16_t hi = (bf16_t)val;
    Tfhi[gid] = hi;
    Tflo[gid] = (bf16_t)(val - (float)hi);
  }
}

// ---------------------------------------------------------------------------
// k_wt: prepack weights for k_mix's B operand (once per launch).
//   Bre[h][m][o][kc], kc=2i -> w1[h,i,o,m], kc=2i+1 -> -w2[h,i,o,m]; bf16 hi/lo.
// Reads coalesced along m; each thread writes 64 B-contiguous kc-spans.
// ---------------------------------------------------------------------------
__global__ __launch_bounds__(256) void k_wt(const float* __restrict__ w1,
                                            const float* __restrict__ w2,
                                            bf16_t* __restrict__ Bwhi,
                                            bf16_t* __restrict__ Bwlo) {
  const int it = blockIdx.x;          // i-tile 0..3 (16 i each)
  const int h = blockIdx.y;
  const int og = blockIdx.z;          // o-group 0..15 (4 o each)
  const int t = threadIdx.x;
  const int m = t & 63, os = t >> 6;
  const int o = og * 4 + os;

  union { bf16_t a[32]; bf16x8 v[4]; } hib, lob;
#pragma unroll
  for (int ii = 0; ii < 16; ++ii) {
    const int i = it * 16 + ii;
    const size_t widx = (((size_t)h * NI + i) * NO + o) * NM + m;
    const float a = w1[widx];
    const float bv = -w2[widx];
    const bf16_t ah = (bf16_t)a;
    const bf16_t bh = (bf16_t)bv;
    hib.a[2 * ii] = ah;     lob.a[2 * ii] = (bf16_t)(a - (float)ah);
    hib.a[2 * ii + 1] = bh; lob.a[2 * ii + 1] = (bf16_t)(bv - (float)bh);
  }
  const size_t dst = (((size_t)h * NM + m) * NO + o) * 128 + it * 32;
#pragma unroll
  for (int j = 0; j < 4; ++j) {
    *(bf16x8*)(Bwhi + dst + j * 8) = hib.v[j];
    *(bf16x8*)(Bwlo + dst + j * 8) = lob.v[j];
  }
}

// ---------------------------------------------------------------------------
// K1: forward truncated DFT as MFMA GEMM.
//   sel[mc][i] = sum_l Tf[mc][l] * q[l][i],  M=128 (mc), N=64 (i), K split LCF.
// Staging: lane -> i (coalesced 256 B q reads per wave); LDS [i][l-pair] u32,
// row stride 34 words (8 B aligned rows, 2-way/free write banks).
// ---------------------------------------------------------------------------
__global__ __launch_bounds__(256) void k_fwd(const float* __restrict__ q,
                                             float* __restrict__ partial,
                                             const bf16_t* __restrict__ Tfhi,
                                             const bf16_t* __restrict__ Tflo,
                                             int LCF, int KCH) {
  const int lc = blockIdx.x, h = blockIdx.y, b = blockIdx.z;
  const int t = threadIdx.x;
  __shared__ uint32_t Bh[64][34], Bl[64][34];

  const int w = t >> 6, lane = t & 63;
  const int arow = lane & 31;        // A: mc row in tile; B: i col in tile
  const int kh = (lane >> 5) << 3;   // k sub-offset: 0 or 8
  const int iA = t & 63;             // staging: this thread's i (lane-contig)
  const int wv = t >> 6;             // staging: wave stages 16 l values

  f32x16 acc[2] = {};                // [i-half]

  const int lbase0 = lc * KCH;
  const bf16_t* Ah = Tfhi + (size_t)(w * 32 + arow) * NL + lbase0 + kh;
  const bf16_t* Al = Tflo + (size_t)(w * 32 + arow) * NL + lbase0 + kh;
  bf16_t* BhP = (bf16_t*)Bh;
  bf16_t* BlP = (bf16_t*)Bl;

  for (int ks = 0; ks < KCH; ks += 64) {
    __syncthreads();  // previous tile's readers done before overwrite
    {
      const float* qp =
          q + (((size_t)b * NL + (lbase0 + ks + wv * 16)) * NH + h) * NI + iA;
      float vv[16];
#pragma unroll
      for (int c = 0; c < 16; ++c) vv[c] = qp[(size_t)c * NH * NI];
#pragma unroll
      for (int c = 0; c < 16; ++c) {
        const int lloc = wv * 16 + c;
        const bf16_t hi = (bf16_t)vv[c];
        const bf16_t lo = (bf16_t)(vv[c] - (float)hi);
        const int w16 = (iA * 34 + (lloc >> 1)) * 2 + (lloc & 1);
        BhP[w16] = hi;
        BlP[w16] = lo;
      }
    }
    __syncthreads();
#pragma unroll
    for (int kk = 0; kk < 4; ++kk) {
      const bf16x8 ah = *(const bf16x8*)(Ah + ks + kk * 16);
      const bf16x8 al = *(const bf16x8*)(Al + ks + kk * 16);
      const int wd = (kk * 16 + kh) >> 1;
      const bf16x8 bh0 = *(const bf16x8*)&Bh[arow][wd];
      const bf16x8 bl0 = *(const bf16x8*)&Bl[arow][wd];
      const bf16x8 bh1 = *(const bf16x8*)&Bh[arow + 32][wd];
      const bf16x8 bl1 = *(const bf16x8*)&Bl[arow + 32][wd];
#define MM(a, bb, c) c = __builtin_amdgcn_mfma_f32_32x32x16_bf16(a, bb, c, 0, 0, 0)
      MM(ah, bh0, acc[0]); MM(ah, bl0, acc[0]); MM(al, bh0, acc[0]);
      MM(ah, bh1, acc[1]); MM(ah, bl1, acc[1]); MM(al, bh1, acc[1]);
#undef MM
    }
  }

  float* pdst = partial + (((size_t)b * NH + h) * LCF + lc) * (NM * NI * 2);
#pragma unroll
  for (int ihf = 0; ihf < 2; ++ihf)
#pragma unroll
    for (int r = 0; r < 16; ++r) {
      const int mc = w * 32 + (r & 3) + 8 * (r >> 2) + 4 * (lane >> 5);
      const int i = arow + ihf * 32;
      pdst[(mc >> 1) * (NI * 2) + i * 2 + (mc & 1)] = acc[ihf][r];
    }
}

// ---------------------------------------------------------------------------
// k_red: reduce partial over lc; emit bf16 hi/lo A-tables for k_mix.
//   A  [h][m][b][kc]: A[2i]=re, A[2i+1]=im
//   Aim[h][m][b][kc]: Aim[2i]=im, Aim[2i+1]=-re   (so Aim*Bre = imag part)
// ---------------------------------------------------------------------------
__global__ __launch_bounds__(256) void k_red(const float* __restrict__ partial,
                                             uint32_t* __restrict__ Ahi,
                                             uint32_t* __restrict__ Alo,
                                             uint32_t* __restrict__ Aimhi,
                                             uint32_t* __restrict__ Aimlo,
                                             int LCF) {
  const int gid = blockIdx.x * 256 + threadIdx.x;  // ((h*64+m)*16+b)*64+i
  const int i = gid & 63, b = (gid >> 6) & 15, m = (gid >> 10) & 63, h = gid >> 16;
  const float* src = partial + ((size_t)b * NH + h) * (size_t)LCF * (NM * NI * 2) +
                     m * (NI * 2) + i * 2;
  float re = 0.f, im = 0.f;
  for (int lc = 0; lc < LCF; ++lc) {
    const float2 v = *(const float2*)(src + (size_t)lc * (NM * NI * 2));
    re += v.x; im += v.y;
  }
  const bf16_t reh = (bf16_t)re, imh = (bf16_t)im;
  const float rel = re - (float)reh, iml = im - (float)imh;
  Ahi[gid] = pk2(re, im);
  Alo[gid] = pk2(rel, iml);
  Aimhi[gid] = pk2(im, -re);
  Aimlo[gid] = pk2(iml, -rel);
}

// ---------------------------------------------------------------------------
// K2: batched MFMA mix. Per (h,m): out2[b][o] = A[b][kc]*Bre[kc][o]
// (re) and Aim*Bre (im). 16x16x32 bf16, hi/lo 3-product. No LDS.
// A-frag: row=lane&15, k=(lane>>4)*8+j (analog of verified 32x32x16);
// C/D: col=lane&15, row=(lane>>4)*4+reg (m89-verified).
// ---------------------------------------------------------------------------
__global__ __launch_bounds__(256) void k_mix(const uint32_t* __restrict__ Ahi,
                                             const uint32_t* __restrict__ Alo,
                                             const uint32_t* __restrict__ Aimhi,
                                             const uint32_t* __restrict__ Aimlo,
                                             const bf16_t* __restrict__ Bwhi,
                                             const bf16_t* __restrict__ Bwlo,
                                             float* __restrict__ out2) {
  const int m = blockIdx.x, h = blockIdx.y;
  const int t = threadIdx.x;
  const int of = t >> 6, lane = t & 63;
  const int row = lane & 15;          // A row = b; B col = o (within frag)
  const int kg = (lane >> 4) << 3;    // k sub-offset 0/8/16/24

  const size_t abase = (((size_t)h * NM + m) * 16 + row) * 64;  // u32 words
  const size_t bbase = (((size_t)h * NM + m) * NO + of * 16 + row) * 128;

  f32x4 accre = {}, accim = {};
#pragma unroll
  for (int ks = 0; ks < 4; ++ks) {
    const int k0 = ks * 32 + kg;
    const bf16x8 ah  = *(const bf16x8*)((const bf16_t*)Ahi + abase * 2 + k0);
    const bf16x8 al  = *(const bf16x8*)((const bf16_t*)Alo + abase * 2 + k0);
    const bf16x8 aih = *(const bf16x8*)((const bf16_t*)Aimhi + abase * 2 + k0);
    const bf16x8 ail = *(const bf16x8*)((const bf16_t*)Aimlo + abase * 2 + k0);
    const bf16x8 bh  = *(const bf16x8*)(Bwhi + bbase + k0);
    const bf16x8 bl  = *(const bf16x8*)(Bwlo + bbase + k0);
#define MM16(a, bb, c) c = __builtin_amdgcn_mfma_f32_16x16x32_bf16(a, bb, c, 0, 0, 0)
    MM16(ah, bh, accre); MM16(al, bh, accre); MM16(ah, bl, accre);
    MM16(aih, bh, accim); MM16(ail, bh, accim); MM16(aih, bl, accim);
#undef MM16
  }

  float2* o2 = (float2*)out2;
  const int o = of * 16 + (lane & 15);
#pragma unroll
  for (int r = 0; r < 4; ++r) {
    const int b = ((lane >> 4) << 2) + r;
    o2[((size_t)b * NH + h) * (NM * NO) + m * NO + o] =
        make_float2(accre[r], accim[r]);
  }
}

// ---------------------------------------------------------------------------
// K3: inverse truncated DFT as MFMA GEMM (unchanged).
// ---------------------------------------------------------------------------
__global__ __launch_bounds__(256) void k_inv(const float* __restrict__ out2,
                                             const bf16_t* __restrict__ Thi,
                                             const bf16_t* __restrict__ Tlo,
                                             float* __restrict__ xout) {
  const int lb = blockIdx.x, h = blockIdx.y, b = blockIdx.z;
  const int t = threadIdx.x;
  __shared__ bf16_t Whi[64 * LDW];
  __shared__ bf16_t Wlo[64 * LDW];

  {  // stage W = fac * out2, transposed to [o][mc], split hi/lo
    const float2* src = (const float2*)out2 + ((size_t)b * NH + h) * (NM * NO);
    for (int u = t; u < NM * NO; u += 256) {
      const int m = u >> 6, o = u & 63;
      const float fac = (m == 0 ? 1.0f : 2.0f) * (1.0f / 4096.0f);
      const float2 cc = src[u];
      const float re = cc.x * fac, im = cc.y * fac;
      const bf16_t reh = (bf16_t)re, imh = (bf16_t)im;
      Whi[o * LDW + 2 * m] = reh;
      Whi[o * LDW + 2 * m + 1] = imh;
      Wlo[o * LDW + 2 * m] = (bf16_t)(re - (float)reh);
      Wlo[o * LDW + 2 * m + 1] = (bf16_t)(im - (float)imh);
    }
  }
  __syncthreads();

  const int w = t >> 6, lane = t & 63;
  const int lrow = lane & 31;
  const int kh = (lane >> 5) << 3;
  const int lwave = (lb << 8) + (w << 6);

  f32x16 acc[2][2] = {};

#pragma unroll
  for (int ks = 0; ks < 8; ++ks) {
    const int kb = ks * 16 + kh;
    const bf16x8 ah0 = *(const bf16x8*)&Whi[lrow * LDW + kb];
    const bf16x8 ah1 = *(const bf16x8*)&Whi[(lrow + 32) * LDW + kb];
    const bf16x8 al0 = *(const bf16x8*)&Wlo[lrow * LDW + kb];
    const bf16x8 al1 = *(const bf16x8*)&Wlo[(lrow + 32) * LDW + kb];
    const size_t r0 = (size_t)(lwave + lrow) * TMC + kb;
    const size_t r1 = (size_t)(lwave + 32 + lrow) * TMC + kb;
    const bf16x8 bh0 = *(const bf16x8*)&Thi[r0];
    const bf16x8 bh1 = *(const bf16x8*)&Thi[r1];
    const bf16x8 bl0 = *(const bf16x8*)&Tlo[r0];
    const bf16x8 bl1 = *(const bf16x8*)&Tlo[r1];
#define MM(a, bb, c) c = __builtin_amdgcn_mfma_f32_32x32x16_bf16(a, bb, c, 0, 0, 0)
    MM(ah0, bh0, acc[0][0]); MM(ah0, bl0, acc[0][0]); MM(al0, bh0, acc[0][0]);
    MM(ah0, bh1, acc[0][1]); MM(ah0, bl1, acc[0][1]); MM(al0, bh1, acc[0][1]);
    MM(ah1, bh0, acc[1][0]); MM(ah1, bl0, acc[1][0]); MM(al1, bh0, acc[1][0]);
    MM(ah1, bh1, acc[1][1]); MM(ah1, bl1, acc[1][1]); MM(al1, bh1, acc[1][1]);
#undef MM
  }

  float* obase = xout + ((size_t)b * NH + h) * NO * (size_t)NL;
#pragma unroll
  for (int of = 0; of < 2; ++of)
#pragma unroll
    for (int lf = 0; lf < 2; ++lf) {
      const int lg = lwave + lf * 32 + lrow;
#pragma unroll
      for (int r = 0; r < 16; ++r) {
        const int o = of * 32 + (r & 3) + 8 * (r >> 2) + 4 * (lane >> 5);
        obase[(size_t)o * NL + lg] = acc[of][lf][r];
      }
    }
}

extern "C" void kernel_launch(void* const* d_in, const int* in_sizes, int n_in,
                              void* d_out, int out_size, void* d_ws, size_t ws_size,
                              hipStream_t stream) {
  const float* q  = (const float*)d_in[0];
  const float* w1 = (const float*)d_in[4];
  const float* w2 = (const float*)d_in[5];
  float* out = (float*)d_out;

  const size_t out2Elems = (size_t)NB * NH * NM * NO * 2;  // 1,048,576 floats
  const size_t tE = 524288;       // bf16 per twiddle table (x4 tables)
  const size_t aW = 524288;       // u32 per A table (x4 tables)
  const size_t bE = 4194304;      // bf16 per weight table (x2 tables)
  const size_t fixedFloats = out2Elems + (4 * tE) / 2 + 4 * aW + (2 * bE) / 2;

  int LCF = 1;
  const int cands[4] = {8, 4, 2, 1};
  for (int ci = 0; ci < 4; ++ci) {
    const size_t pe = (size_t)NB * NH * cands[ci] * NM * NI * 2;
    if ((pe + fixedFloats) * sizeof(float) <= ws_size) { LCF = cands[ci]; break; }
  }
  const size_t partialElems = (size_t)NB * NH * LCF * NM * NI * 2;
  float* partial = (float*)d_ws;
  float* out2 = partial + partialElems;
  bf16_t* Thi = (bf16_t*)(out2 + out2Elems);
  bf16_t* Tlo = Thi + tE;
  bf16_t* Tfhi = Tlo + tE;
  bf16_t* Tflo = Tfhi + tE;
  uint32_t* Ahi = (uint32_t*)(Tflo + tE);
  uint32_t* Alo = Ahi + aW;
  uint32_t* Aimhi = Alo + aW;
  uint32_t* Aimlo = Aimhi + aW;
  bf16_t* Bwhi = (bf16_t*)(Aimlo + aW);
  bf16_t* Bwlo = Bwhi + bE;

  dim3 blk(256);
  k_tab<<<dim3((unsigned)(tE / 256)), blk, 0, stream>>>(Thi, Tlo, Tfhi, Tflo);
  k_wt<<<dim3(4, NH, 16), blk, 0, stream>>>(w1, w2, Bwhi, Bwlo);
  k_fwd<<<dim3(LCF, NH, NB), blk, 0, stream>>>(q, partial, Tfhi, Tflo, LCF, NL / LCF);
  k_red<<<dim3(2048), blk, 0, stream>>>(partial, Ahi, Alo, Aimhi, Aimlo, LCF);
  k_mix<<<dim3(NM, NH), blk, 0, stream>>>(Ahi, Alo, Aimhi, Aimlo, Bwhi, Bwlo, out2);
  k_inv<<<dim3(16, NH, NB), blk, 0, stream>>>(out2, Thi, Tlo, out);
}